// Round 2
// baseline (5251.175 us; speedup 1.0000x reference)
//
#include <hip/hip_runtime.h>
#include <hip/hip_bf16.h>

#define Bdim 4
#define Sdim 1024
#define Ddim 1024
#define Hdim 16
#define HDdim 64

// ---------------- QKV GEMM: x[4096,1024] @ w_attn[1024,3072] + b_attn ----------------
// Routes col segment 0 -> qbuf [B,H,S,HD], segment 1 -> present[0] (k), segment 2 -> present[1] (v)
__global__ __launch_bounds__(256) void gemm_qkv(const float* __restrict__ X,
                                                const float* __restrict__ W,
                                                const float* __restrict__ bias,
                                                float* __restrict__ qbuf,
                                                float* __restrict__ kout,
                                                float* __restrict__ vout) {
    constexpr int BM = 64, BN = 64, BK = 16;
    __shared__ float As[BM][BK + 1];
    __shared__ float Bs[BK][BN + 1];
    const int tid = threadIdx.x;
    const int tx = tid & 15, ty = tid >> 4;
    const int mBase = blockIdx.y * BM;
    const int nBase = blockIdx.x * BN;
    float acc[4][4] = {};
    for (int k0 = 0; k0 < Ddim; k0 += BK) {
        #pragma unroll
        for (int i = 0; i < 4; i++) {
            int idx = tid + i * 256;
            int r = idx >> 4, c = idx & 15;
            As[r][c] = X[(size_t)(mBase + r) * Ddim + k0 + c];
        }
        #pragma unroll
        for (int i = 0; i < 4; i++) {
            int idx = tid + i * 256;
            int r = idx >> 6, c = idx & 63;
            Bs[r][c] = W[(size_t)(k0 + r) * (3 * Ddim) + nBase + c];
        }
        __syncthreads();
        #pragma unroll
        for (int kk = 0; kk < BK; kk++) {
            float a[4], b[4];
            #pragma unroll
            for (int i = 0; i < 4; i++) a[i] = As[ty * 4 + i][kk];
            #pragma unroll
            for (int j = 0; j < 4; j++) b[j] = Bs[kk][tx * 4 + j];
            #pragma unroll
            for (int i = 0; i < 4; i++)
                #pragma unroll
                for (int j = 0; j < 4; j++) acc[i][j] = fmaf(a[i], b[j], acc[i][j]);
        }
        __syncthreads();
    }
    #pragma unroll
    for (int i = 0; i < 4; i++) {
        int m = mBase + ty * 4 + i;
        int bb = m >> 10, s = m & 1023;
        #pragma unroll
        for (int j = 0; j < 4; j++) {
            int n = nBase + tx * 4 + j;
            float v = acc[i][j] + bias[n];
            int seg = n >> 10, nn = n & 1023;
            int h = nn >> 6, d = nn & 63;
            size_t oidx = ((size_t)((bb * Hdim + h) * Sdim + s)) * HDdim + d;
            if (seg == 0) qbuf[oidx] = v;
            else if (seg == 1) kout[oidx] = v;
            else vout[oidx] = v;
        }
    }
}

// ---------------- Attention: one block per (b,h,q) row ----------------
__global__ __launch_bounds__(256) void attn_kernel(const float* __restrict__ qbuf,
                                                   const float* __restrict__ kbuf,
                                                   const float* __restrict__ vbuf,
                                                   const float* __restrict__ ovr,
                                                   const int* __restrict__ msk,
                                                   float* __restrict__ abuf) {
    const int blk = blockIdx.x;           // (b*H + h)*S + q
    const int q = blk & (Sdim - 1);
    const int bh = blk >> 10;             // b*H + h
    const int h = bh & (Hdim - 1);
    const int b = bh >> 4;
    const int tid = threadIdx.x;

    __shared__ float qrow[HDdim];
    __shared__ float w[Sdim];
    __shared__ float red[256];

    const float* kb = kbuf + (size_t)bh * Sdim * HDdim;
    const float* vb = vbuf + (size_t)bh * Sdim * HDdim;

    if (tid < HDdim) qrow[tid] = qbuf[((size_t)bh * Sdim + q) * HDdim + tid];
    __syncthreads();

    // scores: each thread handles keys tid, tid+256, tid+512, tid+768
    float sc[4];
    float smax = -1e30f;
    #pragma unroll
    for (int i = 0; i < 4; i++) {
        int k = tid + i * 256;
        const float* kr = kb + (size_t)k * HDdim;
        float acc = 0.f;
        #pragma unroll
        for (int d = 0; d < HDdim; d++) acc = fmaf(qrow[d], kr[d], acc);
        acc *= 0.125f;   // 1/sqrt(64)
        sc[i] = acc;
        if (k <= q) smax = fmaxf(smax, acc);
    }
    red[tid] = smax;
    __syncthreads();
    for (int s = 128; s > 0; s >>= 1) {
        if (tid < s) red[tid] = fmaxf(red[tid], red[tid + s]);
        __syncthreads();
    }
    const float m = red[0];
    __syncthreads();

    float ssum = 0.f;
    #pragma unroll
    for (int i = 0; i < 4; i++) {
        int k = tid + i * 256;
        float e = (k <= q) ? __expf(sc[i] - m) : 0.f;
        sc[i] = e;
        ssum += e;
    }
    red[tid] = ssum;
    __syncthreads();
    for (int s = 128; s > 0; s >>= 1) {
        if (tid < s) red[tid] += red[tid + s];
        __syncthreads();
    }
    const float inv = 1.f / red[0];

    // final weights with override (override ignores causality! mask is int32)
    const float* orow = ovr + ((size_t)h * Sdim + q) * Sdim;
    const int* mrow = msk + ((size_t)h * Sdim + q) * Sdim;
    #pragma unroll
    for (int i = 0; i < 4; i++) {
        int k = tid + i * 256;
        float val = sc[i] * inv;
        if (mrow[k] != 0) val = orow[k];
        w[k] = val;
    }
    __syncthreads();

    // PV: out[d] = sum_k w[k] * v[k][d]
    const int d = tid & 63;
    const int part = tid >> 6;
    float acc = 0.f;
    const int k0 = part * 256;
    for (int k = k0; k < k0 + 256; k++)
        acc = fmaf(w[k], vb[(size_t)k * HDdim + d], acc);
    red[tid] = acc;
    __syncthreads();
    if (tid < 64) {
        float r = red[tid] + red[tid + 64] + red[tid + 128] + red[tid + 192];
        abuf[((size_t)(b * Sdim + q)) * Ddim + h * HDdim + d] = r;
    }
}

// ---------------- Proj GEMM: abuf[4096,1024] @ w_proj[1024,1024] + b_proj ----------------
__global__ __launch_bounds__(256) void gemm_proj(const float* __restrict__ X,
                                                 const float* __restrict__ W,
                                                 const float* __restrict__ bias,
                                                 float* __restrict__ out) {
    constexpr int BM = 64, BN = 64, BK = 16;
    __shared__ float As[BM][BK + 1];
    __shared__ float Bs[BK][BN + 1];
    const int tid = threadIdx.x;
    const int tx = tid & 15, ty = tid >> 4;
    const int mBase = blockIdx.y * BM;
    const int nBase = blockIdx.x * BN;
    float acc[4][4] = {};
    for (int k0 = 0; k0 < Ddim; k0 += BK) {
        #pragma unroll
        for (int i = 0; i < 4; i++) {
            int idx = tid + i * 256;
            int r = idx >> 4, c = idx & 15;
            As[r][c] = X[(size_t)(mBase + r) * Ddim + k0 + c];
        }
        #pragma unroll
        for (int i = 0; i < 4; i++) {
            int idx = tid + i * 256;
            int r = idx >> 6, c = idx & 63;
            Bs[r][c] = W[(size_t)(k0 + r) * Ddim + nBase + c];
        }
        __syncthreads();
        #pragma unroll
        for (int kk = 0; kk < BK; kk++) {
            float a[4], b[4];
            #pragma unroll
            for (int i = 0; i < 4; i++) a[i] = As[ty * 4 + i][kk];
            #pragma unroll
            for (int j = 0; j < 4; j++) b[j] = Bs[kk][tx * 4 + j];
            #pragma unroll
            for (int i = 0; i < 4; i++)
                #pragma unroll
                for (int j = 0; j < 4; j++) acc[i][j] = fmaf(a[i], b[j], acc[i][j]);
        }
        __syncthreads();
    }
    #pragma unroll
    for (int i = 0; i < 4; i++) {
        int m = mBase + ty * 4 + i;
        #pragma unroll
        for (int j = 0; j < 4; j++) {
            int n = nBase + tx * 4 + j;
            out[(size_t)m * Ddim + n] = acc[i][j] + bias[n];
        }
    }
}

extern "C" void kernel_launch(void* const* d_in, const int* in_sizes, int n_in,
                              void* d_out, int out_size, void* d_ws, size_t ws_size,
                              hipStream_t stream) {
    const float* x       = (const float*)d_in[0];
    const float* w_attn  = (const float*)d_in[1];
    const float* b_attn  = (const float*)d_in[2];
    const float* w_proj  = (const float*)d_in[3];
    const float* b_proj  = (const float*)d_in[4];
    const float* ovr     = (const float*)d_in[5];
    const int*   msk     = (const int*)d_in[6];   // bool mask staged as int32

    float* out = (float*)d_out;
    float* a_out = out;                                     // [B,S,D] = 4194304 floats
    float* kout  = out + (size_t)Bdim * Sdim * Ddim;        // present[0] [B,H,S,HD]
    float* vout  = kout + (size_t)Bdim * Hdim * Sdim * HDdim; // present[1]

    float* qbuf = (float*)d_ws;                             // [B,H,S,HD] 16 MB
    float* abuf = qbuf + (size_t)Bdim * Sdim * Ddim;        // [B,S,D] merged attn out 16 MB

    // 1) QKV GEMM (writes q to ws, k/v straight into present in d_out)
    gemm_qkv<<<dim3(3 * Ddim / 64, Bdim * Sdim / 64), 256, 0, stream>>>(
        x, w_attn, b_attn, qbuf, kout, vout);

    // 2) attention with causal softmax + override
    attn_kernel<<<dim3(Bdim * Hdim * Sdim), 256, 0, stream>>>(
        qbuf, kout, vout, ovr, msk, abuf);

    // 3) output projection
    gemm_proj<<<dim3(Ddim / 64, Bdim * Sdim / 64), 256, 0, stream>>>(
        abuf, w_proj, b_proj, a_out);
}

// Round 4
// 994.438 us; speedup vs baseline: 5.2805x; 5.2805x over previous
//
#include <hip/hip_runtime.h>
#include <hip/hip_bf16.h>

#define Bdim 4
#define Sdim 1024
#define Ddim 1024
#define Hdim 16
#define HDdim 64

typedef __attribute__((ext_vector_type(8))) short short8;   // 8 bf16 = A/B frag
typedef __attribute__((ext_vector_type(4))) float f32x4;    // C/D frag
typedef __attribute__((ext_vector_type(2))) unsigned int uint2v;

__device__ __forceinline__ unsigned short f2bf(float x) {
    unsigned int u = __builtin_bit_cast(unsigned int, x);
    return (unsigned short)((u + 0x7fffu + ((u >> 16) & 1u)) >> 16);  // RNE
}

// ---------------- QKV GEMM: x[4096,1024] @ w_attn[1024,3072] + b_attn ----------------
__global__ __launch_bounds__(256) void gemm_qkv(const float* __restrict__ X,
                                                const float* __restrict__ W,
                                                const float* __restrict__ bias,
                                                float* __restrict__ qbuf,
                                                float* __restrict__ kout,
                                                float* __restrict__ vout) {
    constexpr int BM = 64, BN = 64, BK = 16;
    __shared__ float As[BM][BK + 1];
    __shared__ float Bs[BK][BN + 1];
    const int tid = threadIdx.x;
    const int tx = tid & 15, ty = tid >> 4;
    const int mBase = blockIdx.y * BM;
    const int nBase = blockIdx.x * BN;
    float acc[4][4] = {};
    for (int k0 = 0; k0 < Ddim; k0 += BK) {
        #pragma unroll
        for (int i = 0; i < 4; i++) {
            int idx = tid + i * 256;
            int r = idx >> 4, c = idx & 15;
            As[r][c] = X[(size_t)(mBase + r) * Ddim + k0 + c];
        }
        #pragma unroll
        for (int i = 0; i < 4; i++) {
            int idx = tid + i * 256;
            int r = idx >> 6, c = idx & 63;
            Bs[r][c] = W[(size_t)(k0 + r) * (3 * Ddim) + nBase + c];
        }
        __syncthreads();
        #pragma unroll
        for (int kk = 0; kk < BK; kk++) {
            float a[4], b[4];
            #pragma unroll
            for (int i = 0; i < 4; i++) a[i] = As[ty * 4 + i][kk];
            #pragma unroll
            for (int j = 0; j < 4; j++) b[j] = Bs[kk][tx * 4 + j];
            #pragma unroll
            for (int i = 0; i < 4; i++)
                #pragma unroll
                for (int j = 0; j < 4; j++) acc[i][j] = fmaf(a[i], b[j], acc[i][j]);
        }
        __syncthreads();
    }
    #pragma unroll
    for (int i = 0; i < 4; i++) {
        int m = mBase + ty * 4 + i;
        int bb = m >> 10, s = m & 1023;
        #pragma unroll
        for (int j = 0; j < 4; j++) {
            int n = nBase + tx * 4 + j;
            float v = acc[i][j] + bias[n];
            int seg = n >> 10, nn = n & 1023;
            int h = nn >> 6, d = nn & 63;
            size_t oidx = ((size_t)((bb * Hdim + h) * Sdim + s)) * HDdim + d;
            if (seg == 0) qbuf[oidx] = v;
            else if (seg == 1) kout[oidx] = v;
            else vout[oidx] = v;
        }
    }
}

// ---------------- MFMA attention ----------------
// Block: (qt, bh). 4 waves, wave wq owns q-strip qt*64 + wq*16 + [0,16).
// S^T = K*Q^T so each lane owns q-row (lane&15): softmax stats lane-local.
__global__ __launch_bounds__(256) void attn_mfma(const float* __restrict__ qbuf,
                                                 const float* __restrict__ kbuf,
                                                 const float* __restrict__ vbuf,
                                                 const float* __restrict__ ovr,
                                                 const int* __restrict__ msk,
                                                 float* __restrict__ abuf) {
    const int qt = blockIdx.x;          // 0..15
    const int bh = blockIdx.y;          // 0..63
    const int h = bh & (Hdim - 1);
    const int b = bh >> 4;
    const int tid = threadIdx.x;
    const int wq = tid >> 6;
    const int lane = tid & 63;
    const int l15 = lane & 15;
    const int lg = lane >> 4;           // 0..3

    __shared__ unsigned short Ks[64 * 64];     // [k][d] bf16, XOR-swizzled rows
    __shared__ unsigned short Vt[64 * 64];     // [d][k] bf16 (transposed), swizzled
    __shared__ unsigned short Ps[4][16 * 64];  // per-wave P [q][k] bf16, swizzled

    const float* kb = kbuf + (size_t)bh * Sdim * HDdim;
    const float* vb = vbuf + (size_t)bh * Sdim * HDdim;
    const int qrow = qt * 64 + wq * 16 + l15;  // this lane's q-row

    // Q B-fragments, scale 1/8 folded (exact): elem i of frag f <-> d = 8*lg+32*f+i
    short8 qf[2];
    {
        const float* qr = qbuf + ((size_t)bh * Sdim + qrow) * HDdim;
        #pragma unroll
        for (int f = 0; f < 2; f++) {
            union { short8 v; unsigned short u[8]; } t;
            #pragma unroll
            for (int i = 0; i < 8; i++)
                t.u[i] = f2bf(qr[8 * lg + 32 * f + i] * 0.125f);
            qf[f] = t.v;
        }
    }

    auto stageK = [&](int kt) {
        #pragma unroll
        for (int j = 0; j < 4; j++) {
            int idx = tid + j * 256;
            int k = idx >> 4;
            int d0 = (idx & 15) * 4;
            float4 v = *(const float4*)(kb + (size_t)(kt * 64 + k) * HDdim + d0);
            uint2v p;
            p.x = (unsigned)f2bf(v.x) | ((unsigned)f2bf(v.y) << 16);
            p.y = (unsigned)f2bf(v.z) | ((unsigned)f2bf(v.w) << 16);
            int byte = k * 128 + d0 * 2;
            byte ^= (k & 7) << 4;
            *(uint2v*)((char*)Ks + byte) = p;
        }
    };
    auto stageV = [&](int kt) {   // transpose 4x1 in regs; coalesced global reads
        int d = tid & 63;
        int k00 = 4 * (tid >> 6);
        #pragma unroll
        for (int j = 0; j < 4; j++) {
            int k0 = k00 + 16 * j;
            float v0 = vb[(size_t)(kt * 64 + k0 + 0) * HDdim + d];
            float v1 = vb[(size_t)(kt * 64 + k0 + 1) * HDdim + d];
            float v2 = vb[(size_t)(kt * 64 + k0 + 2) * HDdim + d];
            float v3 = vb[(size_t)(kt * 64 + k0 + 3) * HDdim + d];
            uint2v p;
            p.x = (unsigned)f2bf(v0) | ((unsigned)f2bf(v1) << 16);
            p.y = (unsigned)f2bf(v2) | ((unsigned)f2bf(v3) << 16);
            int byte = d * 128 + k0 * 2;
            byte ^= (d & 7) << 4;
            *(uint2v*)((char*)Vt + byte) = p;
        }
    };
    auto readfrag = [&](const unsigned short* base, int row, int f) -> short8 {
        int byte = row * 128 + lg * 16 + f * 64;
        byte ^= (row & 7) << 4;
        return *(const short8*)((const char*)base + byte);
    };

    // ---- Sweep 1: causal online (m,l) per q-row, registers only ----
    float m_run = -1e30f, l_run = 0.f;
    for (int kt = 0; kt <= qt; kt++) {
        __syncthreads();
        stageK(kt);
        __syncthreads();
        float sv[16];
        const bool diag = (kt == qt);
        #pragma unroll
        for (int ks = 0; ks < 4; ks++) {
            f32x4 c = {0.f, 0.f, 0.f, 0.f};
            short8 a0 = readfrag(Ks, l15 + 16 * ks, 0);
            short8 a1 = readfrag(Ks, l15 + 16 * ks, 1);
            c = __builtin_amdgcn_mfma_f32_16x16x32_bf16(a0, qf[0], c, 0, 0, 0);
            c = __builtin_amdgcn_mfma_f32_16x16x32_bf16(a1, qf[1], c, 0, 0, 0);
            #pragma unroll
            for (int r = 0; r < 4; r++) {
                int kg = kt * 64 + ks * 16 + 4 * lg + r;
                float s = c[r];
                if (diag && kg > qrow) s = -1e30f;
                sv[ks * 4 + r] = s;
            }
        }
        float tm = -1e30f;
        #pragma unroll
        for (int i = 0; i < 16; i++) tm = fmaxf(tm, sv[i]);
        tm = fmaxf(tm, __shfl_xor(tm, 16));
        tm = fmaxf(tm, __shfl_xor(tm, 32));
        float mn = fmaxf(m_run, tm);
        float ts = 0.f;
        #pragma unroll
        for (int i = 0; i < 16; i++) ts += __expf(sv[i] - mn);
        ts += __shfl_xor(ts, 16);
        ts += __shfl_xor(ts, 32);
        l_run = l_run * __expf(m_run - mn) + ts;
        m_run = mn;
    }
    const float inv_l = 1.f / l_run;

    // ---- Sweep 2: all 16 k-tiles (override ignores causality) ----
    f32x4 acc[4];
    #pragma unroll
    for (int ds = 0; ds < 4; ds++) acc[ds] = (f32x4){0.f, 0.f, 0.f, 0.f};
    const float* ob_base = ovr + ((size_t)h * Sdim + qrow) * Sdim;
    const int* mb_base = msk + ((size_t)h * Sdim + qrow) * Sdim;

    for (int kt = 0; kt < 16; kt++) {
        __syncthreads();
        if (kt <= qt) stageK(kt);
        stageV(kt);
        __syncthreads();

        float w[16];
        if (kt <= qt) {
            const bool diag = (kt == qt);
            #pragma unroll
            for (int ks = 0; ks < 4; ks++) {
                f32x4 c = {0.f, 0.f, 0.f, 0.f};
                short8 a0 = readfrag(Ks, l15 + 16 * ks, 0);
                short8 a1 = readfrag(Ks, l15 + 16 * ks, 1);
                c = __builtin_amdgcn_mfma_f32_16x16x32_bf16(a0, qf[0], c, 0, 0, 0);
                c = __builtin_amdgcn_mfma_f32_16x16x32_bf16(a1, qf[1], c, 0, 0, 0);
                #pragma unroll
                for (int r = 0; r < 4; r++) {
                    int kg = kt * 64 + ks * 16 + 4 * lg + r;
                    float p = __expf(c[r] - m_run) * inv_l;
                    if (diag && kg > qrow) p = 0.f;
                    w[ks * 4 + r] = p;
                }
            }
        } else {
            #pragma unroll
            for (int i = 0; i < 16; i++) w[i] = 0.f;
        }
        // override: w = mask ? ovr : w   (vectorized: r=0..3 are 4 consecutive k)
        #pragma unroll
        for (int ks = 0; ks < 4; ks++) {
            int kb0 = kt * 64 + ks * 16 + 4 * lg;
            float4 o4 = *(const float4*)(ob_base + kb0);
            int4 m4 = *(const int4*)(mb_base + kb0);
            if (m4.x) w[ks * 4 + 0] = o4.x;
            if (m4.y) w[ks * 4 + 1] = o4.y;
            if (m4.z) w[ks * 4 + 2] = o4.z;
            if (m4.w) w[ks * 4 + 3] = o4.w;
        }
        // store P (bf16) to this wave's LDS region: row q=l15, col k
        #pragma unroll
        for (int ks = 0; ks < 4; ks++) {
            #pragma unroll
            for (int r = 0; r < 4; r++) {
                int kloc = ks * 16 + 4 * lg + r;
                int byte = l15 * 128 + kloc * 2;
                byte ^= (l15 & 7) << 4;
                *(unsigned short*)((char*)(Ps[wq]) + byte) = f2bf(w[ks * 4 + r]);
            }
        }
        // PV: out[q][d] += P[q][k] * V[k][d]   (wave-local; compiler emits lgkmcnt)
        short8 pa0 = readfrag(Ps[wq], l15, 0);
        short8 pa1 = readfrag(Ps[wq], l15, 1);
        #pragma unroll
        for (int ds = 0; ds < 4; ds++) {
            short8 v0 = readfrag(Vt, l15 + 16 * ds, 0);
            short8 v1 = readfrag(Vt, l15 + 16 * ds, 1);
            acc[ds] = __builtin_amdgcn_mfma_f32_16x16x32_bf16(pa0, v0, acc[ds], 0, 0, 0);
            acc[ds] = __builtin_amdgcn_mfma_f32_16x16x32_bf16(pa1, v1, acc[ds], 0, 0, 0);
        }
    }

    // epilogue: C layout row=4*lg+r (q), col=l15 (d)
    #pragma unroll
    for (int ds = 0; ds < 4; ds++) {
        #pragma unroll
        for (int r = 0; r < 4; r++) {
            int q = qt * 64 + wq * 16 + 4 * lg + r;
            int d = h * HDdim + ds * 16 + l15;
            abuf[((size_t)(b * Sdim + q)) * Ddim + d] = acc[ds][r];
        }
    }
}

// ---------------- Proj GEMM: abuf[4096,1024] @ w_proj[1024,1024] + b_proj ----------------
__global__ __launch_bounds__(256) void gemm_proj(const float* __restrict__ X,
                                                 const float* __restrict__ W,
                                                 const float* __restrict__ bias,
                                                 float* __restrict__ out) {
    constexpr int BM = 64, BN = 64, BK = 16;
    __shared__ float As[BM][BK + 1];
    __shared__ float Bs[BK][BN + 1];
    const int tid = threadIdx.x;
    const int tx = tid & 15, ty = tid >> 4;
    const int mBase = blockIdx.y * BM;
    const int nBase = blockIdx.x * BN;
    float acc[4][4] = {};
    for (int k0 = 0; k0 < Ddim; k0 += BK) {
        #pragma unroll
        for (int i = 0; i < 4; i++) {
            int idx = tid + i * 256;
            int r = idx >> 4, c = idx & 15;
            As[r][c] = X[(size_t)(mBase + r) * Ddim + k0 + c];
        }
        #pragma unroll
        for (int i = 0; i < 4; i++) {
            int idx = tid + i * 256;
            int r = idx >> 6, c = idx & 63;
            Bs[r][c] = W[(size_t)(k0 + r) * Ddim + nBase + c];
        }
        __syncthreads();
        #pragma unroll
        for (int kk = 0; kk < BK; kk++) {
            float a[4], b[4];
            #pragma unroll
            for (int i = 0; i < 4; i++) a[i] = As[ty * 4 + i][kk];
            #pragma unroll
            for (int j = 0; j < 4; j++) b[j] = Bs[kk][tx * 4 + j];
            #pragma unroll
            for (int i = 0; i < 4; i++)
                #pragma unroll
                for (int j = 0; j < 4; j++) acc[i][j] = fmaf(a[i], b[j], acc[i][j]);
        }
        __syncthreads();
    }
    #pragma unroll
    for (int i = 0; i < 4; i++) {
        int m = mBase + ty * 4 + i;
        #pragma unroll
        for (int j = 0; j < 4; j++) {
            int n = nBase + tx * 4 + j;
            out[(size_t)m * Ddim + n] = acc[i][j] + bias[n];
        }
    }
}

extern "C" void kernel_launch(void* const* d_in, const int* in_sizes, int n_in,
                              void* d_out, int out_size, void* d_ws, size_t ws_size,
                              hipStream_t stream) {
    const float* x       = (const float*)d_in[0];
    const float* w_attn  = (const float*)d_in[1];
    const float* b_attn  = (const float*)d_in[2];
    const float* w_proj  = (const float*)d_in[3];
    const float* b_proj  = (const float*)d_in[4];
    const float* ovr     = (const float*)d_in[5];
    const int*   msk     = (const int*)d_in[6];   // bool mask staged as int32

    float* out = (float*)d_out;
    float* a_out = out;                                       // [B,S,D]
    float* kout  = out + (size_t)Bdim * Sdim * Ddim;          // present[0] [B,H,S,HD]
    float* vout  = kout + (size_t)Bdim * Hdim * Sdim * HDdim; // present[1]

    float* qbuf = (float*)d_ws;                               // [B,H,S,HD] 16 MB
    float* abuf = qbuf + (size_t)Bdim * Sdim * Ddim;          // [B,S,D] 16 MB

    gemm_qkv<<<dim3(3 * Ddim / 64, Bdim * Sdim / 64), 256, 0, stream>>>(
        x, w_attn, b_attn, qbuf, kout, vout);

    attn_mfma<<<dim3(Sdim / 64, Bdim * Hdim), 256, 0, stream>>>(
        qbuf, kout, vout, ovr, msk, abuf);

    gemm_proj<<<dim3(Ddim / 64, Bdim * Sdim / 64), 256, 0, stream>>>(
        abuf, w_proj, b_proj, a_out);
}

// Round 5
// 413.817 us; speedup vs baseline: 12.6896x; 2.4031x over previous
//
#include <hip/hip_runtime.h>
#include <hip/hip_bf16.h>

#define Bdim 4
#define Sdim 1024
#define Ddim 1024
#define Hdim 16
#define HDdim 64

typedef __attribute__((ext_vector_type(8))) short short8;   // 8 bf16 = A/B frag
typedef __attribute__((ext_vector_type(4))) float f32x4;    // C/D frag
typedef __attribute__((ext_vector_type(2))) unsigned int uint2v;

#define AS1 __attribute__((address_space(1)))
#define AS3 __attribute__((address_space(3)))

__device__ __forceinline__ unsigned short f2bf(float x) {
    unsigned int u = __builtin_bit_cast(unsigned int, x);
    return (unsigned short)((u + 0x7fffu + ((u >> 16) & 1u)) >> 16);  // RNE
}

// ---------------- fp32 -> bf16 elementwise (x) ----------------
__global__ __launch_bounds__(256) void conv_bf16(const float* __restrict__ in,
                                                 unsigned short* __restrict__ out) {
    int i = blockIdx.x * 256 + threadIdx.x;
    float4 v = ((const float4*)in)[i];
    uint2v p;
    p.x = (unsigned)f2bf(v.x) | ((unsigned)f2bf(v.y) << 16);
    p.y = (unsigned)f2bf(v.z) | ((unsigned)f2bf(v.w) << 16);
    ((uint2v*)out)[i] = p;
}

// ---------------- fp32 [K][N] -> bf16 transposed [N][K] ----------------
__global__ __launch_bounds__(256) void transpose_bf16(const float* __restrict__ W,
                                                      unsigned short* __restrict__ Wt,
                                                      int K, int N) {
    __shared__ float t[32][33];
    const int tk = blockIdx.y * 32, tn = blockIdx.x * 32;
    const int r = threadIdx.x >> 5, c = threadIdx.x & 31;
    #pragma unroll
    for (int j = 0; j < 4; j++)
        t[r + 8 * j][c] = W[(size_t)(tk + r + 8 * j) * N + tn + c];
    __syncthreads();
    #pragma unroll
    for (int j = 0; j < 4; j++) {
        int nn = r + 8 * j;
        Wt[(size_t)(tn + nn) * K + tk + c] = f2bf(t[c][nn]);
    }
}

// ---------------- bf16 MFMA GEMM body (m97 structure) ----------------
// A [M][1024] bf16 K-contig, Bt [N][1024] bf16 K-contig. 128x128 tile, BK=32.
// 4 waves 2x2; per-wave 64x64 = 4x4 16x16 frags.
#define GEMM_BODY(Aptr, Bptr)                                                          \
    __shared__ unsigned short As[128 * 32];                                            \
    __shared__ unsigned short Bs[128 * 32];                                            \
    const int tid = threadIdx.x;                                                       \
    const int lane = tid & 63, w = tid >> 6;                                           \
    const int wm = w >> 1, wn = w & 1;                                                 \
    const int l15 = lane & 15, lg = lane >> 4;                                         \
    const int tile_m = blockIdx.y * 128, tile_n = blockIdx.x * 128;                    \
    f32x4 acc[4][4] = {};                                                              \
    for (int k0 = 0; k0 < 1024; k0 += 32) {                                            \
        _Pragma("unroll")                                                              \
        for (int j = 0; j < 2; j++) {                                                  \
            int ca = j * 256 + tid;                                                    \
            int rowa = ca >> 2, offa = (ca & 3) * 16;                                  \
            const char* ga = (const char*)(Aptr) +                                     \
                ((size_t)(tile_m + rowa) * 1024 + k0) * 2 + offa;                      \
            char* la = (char*)As + (j * 256 + w * 64) * 16;                            \
            __builtin_amdgcn_global_load_lds((const AS1 void*)ga, (AS3 void*)la,       \
                                             16, 0, 0);                                \
            const char* gb = (const char*)(Bptr) +                                     \
                ((size_t)(tile_n + rowa) * 1024 + k0) * 2 + offa;                      \
            char* lb = (char*)Bs + (j * 256 + w * 64) * 16;                            \
            __builtin_amdgcn_global_load_lds((const AS1 void*)gb, (AS3 void*)lb,       \
                                             16, 0, 0);                                \
        }                                                                              \
        __syncthreads();                                                               \
        short8 af[4], bfr[4];                                                          \
        _Pragma("unroll")                                                              \
        for (int t4 = 0; t4 < 4; t4++) {                                               \
            af[t4] = *(const short8*)((const char*)As +                                \
                        (wm * 64 + t4 * 16 + l15) * 64 + lg * 16);                     \
            bfr[t4] = *(const short8*)((const char*)Bs +                               \
                        (wn * 64 + t4 * 16 + l15) * 64 + lg * 16);                     \
        }                                                                              \
        _Pragma("unroll")                                                              \
        for (int i = 0; i < 4; i++)                                                    \
            _Pragma("unroll")                                                          \
            for (int j2 = 0; j2 < 4; j2++)                                             \
                acc[i][j2] = __builtin_amdgcn_mfma_f32_16x16x32_bf16(                  \
                    af[i], bfr[j2], acc[i][j2], 0, 0, 0);                              \
        __syncthreads();                                                               \
    }

// QKV: N=3072, routes q (bf16, pre-scaled 1/8) / k / v
__global__ __launch_bounds__(256) void gemm_qkv_mfma(const unsigned short* __restrict__ Xb,
                                                     const unsigned short* __restrict__ Wt,
                                                     const float* __restrict__ bias,
                                                     unsigned short* __restrict__ qbuf,
                                                     float* __restrict__ kout,
                                                     float* __restrict__ vout) {
    GEMM_BODY(Xb, Wt)
    const int seg = tile_n >> 10;   // uniform per block (tile never crosses 1024)
    #pragma unroll
    for (int i = 0; i < 4; i++) {
        #pragma unroll
        for (int j2 = 0; j2 < 4; j2++) {
            int n = tile_n + wn * 64 + j2 * 16 + l15;
            float bv = bias[n];
            int nn = n & 1023, h = nn >> 6, d = nn & 63;
            #pragma unroll
            for (int r = 0; r < 4; r++) {
                int m = tile_m + wm * 64 + i * 16 + 4 * lg + r;
                float v = acc[i][j2][r] + bv;
                int bb = m >> 10, s = m & 1023;
                size_t oidx = ((size_t)((bb * Hdim + h) * Sdim + s)) * HDdim + d;
                if (seg == 0) qbuf[oidx] = f2bf(v * 0.125f);
                else if (seg == 1) kout[oidx] = v;
                else vout[oidx] = v;
            }
        }
    }
}

// Proj: N=1024, plain fp32 out + bias
__global__ __launch_bounds__(256) void gemm_proj_mfma(const unsigned short* __restrict__ Ab,
                                                      const unsigned short* __restrict__ Wt,
                                                      const float* __restrict__ bias,
                                                      float* __restrict__ out) {
    GEMM_BODY(Ab, Wt)
    #pragma unroll
    for (int i = 0; i < 4; i++) {
        #pragma unroll
        for (int j2 = 0; j2 < 4; j2++) {
            int n = tile_n + wn * 64 + j2 * 16 + l15;
            float bv = bias[n];
            #pragma unroll
            for (int r = 0; r < 4; r++) {
                int m = tile_m + wm * 64 + i * 16 + 4 * lg + r;
                out[(size_t)m * Ddim + n] = acc[i][j2][r] + bv;
            }
        }
    }
}

// ---------------- MFMA attention (qbuf bf16 pre-scaled; abuf bf16 out) ----------------
__global__ __launch_bounds__(256) void attn_mfma(const unsigned short* __restrict__ qbuf,
                                                 const float* __restrict__ kbuf,
                                                 const float* __restrict__ vbuf,
                                                 const float* __restrict__ ovr,
                                                 const int* __restrict__ msk,
                                                 unsigned short* __restrict__ abuf) {
    const int qt = blockIdx.x;          // 0..15
    const int bh = blockIdx.y;          // 0..63
    const int h = bh & (Hdim - 1);
    const int b = bh >> 4;
    const int tid = threadIdx.x;
    const int wq = tid >> 6;
    const int lane = tid & 63;
    const int l15 = lane & 15;
    const int lg = lane >> 4;           // 0..3

    __shared__ unsigned short Ks[64 * 64];     // [k][d] bf16, XOR-swizzled rows
    __shared__ unsigned short Vt[64 * 64];     // [d][k] bf16 (transposed), swizzled
    __shared__ unsigned short Ps[4][16 * 64];  // per-wave P [q][k] bf16, swizzled

    const float* kb = kbuf + (size_t)bh * Sdim * HDdim;
    const float* vb = vbuf + (size_t)bh * Sdim * HDdim;
    const int qrow = qt * 64 + wq * 16 + l15;  // this lane's q-row

    // Q B-fragments (bf16, 1/8 pre-folded by gemm_qkv): d = 8*lg+32*f+i
    short8 qf[2];
    {
        const unsigned short* qr = qbuf + ((size_t)bh * Sdim + qrow) * HDdim;
        qf[0] = *(const short8*)(qr + 8 * lg);
        qf[1] = *(const short8*)(qr + 8 * lg + 32);
    }

    auto stageK = [&](int kt) {
        #pragma unroll
        for (int j = 0; j < 4; j++) {
            int idx = tid + j * 256;
            int k = idx >> 4;
            int d0 = (idx & 15) * 4;
            float4 v = *(const float4*)(kb + (size_t)(kt * 64 + k) * HDdim + d0);
            uint2v p;
            p.x = (unsigned)f2bf(v.x) | ((unsigned)f2bf(v.y) << 16);
            p.y = (unsigned)f2bf(v.z) | ((unsigned)f2bf(v.w) << 16);
            int byte = k * 128 + d0 * 2;
            byte ^= (k & 7) << 4;
            *(uint2v*)((char*)Ks + byte) = p;
        }
    };
    auto stageV = [&](int kt) {   // transpose 4x1 in regs; coalesced global reads
        int d = tid & 63;
        int k00 = 4 * (tid >> 6);
        #pragma unroll
        for (int j = 0; j < 4; j++) {
            int k0 = k00 + 16 * j;
            float v0 = vb[(size_t)(kt * 64 + k0 + 0) * HDdim + d];
            float v1 = vb[(size_t)(kt * 64 + k0 + 1) * HDdim + d];
            float v2 = vb[(size_t)(kt * 64 + k0 + 2) * HDdim + d];
            float v3 = vb[(size_t)(kt * 64 + k0 + 3) * HDdim + d];
            uint2v p;
            p.x = (unsigned)f2bf(v0) | ((unsigned)f2bf(v1) << 16);
            p.y = (unsigned)f2bf(v2) | ((unsigned)f2bf(v3) << 16);
            int byte = d * 128 + k0 * 2;
            byte ^= (d & 7) << 4;
            *(uint2v*)((char*)Vt + byte) = p;
        }
    };
    auto readfrag = [&](const unsigned short* base, int row, int f) -> short8 {
        int byte = row * 128 + lg * 16 + f * 64;
        byte ^= (row & 7) << 4;
        return *(const short8*)((const char*)base + byte);
    };

    // ---- Sweep 1: causal online (m,l) per q-row, registers only ----
    float m_run = -1e30f, l_run = 0.f;
    for (int kt = 0; kt <= qt; kt++) {
        __syncthreads();
        stageK(kt);
        __syncthreads();
        float sv[16];
        const bool diag = (kt == qt);
        #pragma unroll
        for (int ks = 0; ks < 4; ks++) {
            f32x4 c = {0.f, 0.f, 0.f, 0.f};
            short8 a0 = readfrag(Ks, l15 + 16 * ks, 0);
            short8 a1 = readfrag(Ks, l15 + 16 * ks, 1);
            c = __builtin_amdgcn_mfma_f32_16x16x32_bf16(a0, qf[0], c, 0, 0, 0);
            c = __builtin_amdgcn_mfma_f32_16x16x32_bf16(a1, qf[1], c, 0, 0, 0);
            #pragma unroll
            for (int r = 0; r < 4; r++) {
                int kg = kt * 64 + ks * 16 + 4 * lg + r;
                float s = c[r];
                if (diag && kg > qrow) s = -1e30f;
                sv[ks * 4 + r] = s;
            }
        }
        float tm = -1e30f;
        #pragma unroll
        for (int i = 0; i < 16; i++) tm = fmaxf(tm, sv[i]);
        tm = fmaxf(tm, __shfl_xor(tm, 16));
        tm = fmaxf(tm, __shfl_xor(tm, 32));
        float mn = fmaxf(m_run, tm);
        float ts = 0.f;
        #pragma unroll
        for (int i = 0; i < 16; i++) ts += __expf(sv[i] - mn);
        ts += __shfl_xor(ts, 16);
        ts += __shfl_xor(ts, 32);
        l_run = l_run * __expf(m_run - mn) + ts;
        m_run = mn;
    }
    const float inv_l = 1.f / l_run;

    // ---- Sweep 2: all 16 k-tiles (override ignores causality) ----
    f32x4 acc[4];
    #pragma unroll
    for (int ds = 0; ds < 4; ds++) acc[ds] = (f32x4){0.f, 0.f, 0.f, 0.f};
    const float* ob_base = ovr + ((size_t)h * Sdim + qrow) * Sdim;
    const int* mb_base = msk + ((size_t)h * Sdim + qrow) * Sdim;

    for (int kt = 0; kt < 16; kt++) {
        __syncthreads();
        if (kt <= qt) stageK(kt);
        stageV(kt);
        __syncthreads();

        float w[16];
        if (kt <= qt) {
            const bool diag = (kt == qt);
            #pragma unroll
            for (int ks = 0; ks < 4; ks++) {
                f32x4 c = {0.f, 0.f, 0.f, 0.f};
                short8 a0 = readfrag(Ks, l15 + 16 * ks, 0);
                short8 a1 = readfrag(Ks, l15 + 16 * ks, 1);
                c = __builtin_amdgcn_mfma_f32_16x16x32_bf16(a0, qf[0], c, 0, 0, 0);
                c = __builtin_amdgcn_mfma_f32_16x16x32_bf16(a1, qf[1], c, 0, 0, 0);
                #pragma unroll
                for (int r = 0; r < 4; r++) {
                    int kg = kt * 64 + ks * 16 + 4 * lg + r;
                    float p = __expf(c[r] - m_run) * inv_l;
                    if (diag && kg > qrow) p = 0.f;
                    w[ks * 4 + r] = p;
                }
            }
        } else {
            #pragma unroll
            for (int i = 0; i < 16; i++) w[i] = 0.f;
        }
        // override: w = mask ? ovr : w
        #pragma unroll
        for (int ks = 0; ks < 4; ks++) {
            int kb0 = kt * 64 + ks * 16 + 4 * lg;
            float4 o4 = *(const float4*)(ob_base + kb0);
            int4 m4 = *(const int4*)(mb_base + kb0);
            if (m4.x) w[ks * 4 + 0] = o4.x;
            if (m4.y) w[ks * 4 + 1] = o4.y;
            if (m4.z) w[ks * 4 + 2] = o4.z;
            if (m4.w) w[ks * 4 + 3] = o4.w;
        }
        // store P (bf16) to this wave's LDS region: row q=l15, col k
        #pragma unroll
        for (int ks = 0; ks < 4; ks++) {
            #pragma unroll
            for (int r = 0; r < 4; r++) {
                int kloc = ks * 16 + 4 * lg + r;
                int byte = l15 * 128 + kloc * 2;
                byte ^= (l15 & 7) << 4;
                *(unsigned short*)((char*)(Ps[wq]) + byte) = f2bf(w[ks * 4 + r]);
            }
        }
        // PV: out[q][d] += P[q][k] * V[k][d]
        short8 pa0 = readfrag(Ps[wq], l15, 0);
        short8 pa1 = readfrag(Ps[wq], l15, 1);
        #pragma unroll
        for (int ds = 0; ds < 4; ds++) {
            short8 v0 = readfrag(Vt, l15 + 16 * ds, 0);
            short8 v1 = readfrag(Vt, l15 + 16 * ds, 1);
            acc[ds] = __builtin_amdgcn_mfma_f32_16x16x32_bf16(pa0, v0, acc[ds], 0, 0, 0);
            acc[ds] = __builtin_amdgcn_mfma_f32_16x16x32_bf16(pa1, v1, acc[ds], 0, 0, 0);
        }
    }

    // epilogue: C layout row=4*lg+r (q), col=l15 (d); write bf16 for proj A-operand
    #pragma unroll
    for (int ds = 0; ds < 4; ds++) {
        #pragma unroll
        for (int r = 0; r < 4; r++) {
            int q = qt * 64 + wq * 16 + 4 * lg + r;
            int d = h * HDdim + ds * 16 + l15;
            abuf[((size_t)(b * Sdim + q)) * Ddim + d] = f2bf(acc[ds][r]);
        }
    }
}

extern "C" void kernel_launch(void* const* d_in, const int* in_sizes, int n_in,
                              void* d_out, int out_size, void* d_ws, size_t ws_size,
                              hipStream_t stream) {
    const float* x       = (const float*)d_in[0];
    const float* w_attn  = (const float*)d_in[1];
    const float* b_attn  = (const float*)d_in[2];
    const float* w_proj  = (const float*)d_in[3];
    const float* b_proj  = (const float*)d_in[4];
    const float* ovr     = (const float*)d_in[5];
    const int*   msk     = (const int*)d_in[6];

    float* out = (float*)d_out;
    float* a_out = out;                                       // [B,S,D]
    float* kout  = out + (size_t)Bdim * Sdim * Ddim;          // present[0] [B,H,S,HD]
    float* vout  = kout + (size_t)Bdim * Hdim * Sdim * HDdim; // present[1]

    char* ws = (char*)d_ws;
    unsigned short* qbuf = (unsigned short*)ws;               // 8 MB  [B,H,S,HD] bf16 *0.125
    unsigned short* abuf = (unsigned short*)(ws + (8  << 20)); // 8 MB  [B,S,D] bf16
    unsigned short* Xb   = (unsigned short*)(ws + (16 << 20)); // 8 MB  x bf16
    unsigned short* Wta  = (unsigned short*)(ws + (24 << 20)); // 6 MB  w_attn^T bf16 [3072][1024]
    unsigned short* Wtp  = (unsigned short*)(ws + (30 << 20)); // 2 MB  w_proj^T bf16 [1024][1024]

    // prep: bf16 conversions (+ weight transposes)
    conv_bf16<<<dim3(4096), 256, 0, stream>>>(x, Xb);
    transpose_bf16<<<dim3(96, 32), 256, 0, stream>>>(w_attn, Wta, 1024, 3072);
    transpose_bf16<<<dim3(32, 32), 256, 0, stream>>>(w_proj, Wtp, 1024, 1024);

    // 1) QKV GEMM (MFMA)
    gemm_qkv_mfma<<<dim3(24, 32), 256, 0, stream>>>(Xb, Wta, b_attn, qbuf, kout, vout);

    // 2) attention
    attn_mfma<<<dim3(16, 64), 256, 0, stream>>>(qbuf, kout, vout, ovr, msk, abuf);

    // 3) output projection (MFMA)
    gemm_proj_mfma<<<dim3(8, 32), 256, 0, stream>>>(abuf, Wtp, b_proj, a_out);
}